// Round 11
// baseline (213.209 us; speedup 1.0000x reference)
//
#include <hip/hip_runtime.h>

// RobustAttention: blockwise (w=15) causal cosFormer linear attention.
// scores[l,j] = cos(th_l - th_j) * <relu(q_l), relu(k_j)>, j<=l
// out[l] = sum_j scores[l,j] * relu(v_j) / max(sum_j scores[l,j], 1e-6)
//
// R14: every scheduling lever is exhausted and flat (occupancy x2: flat;
// q-coalesce: +3%; wave-decoupling: flat; barriers 3->1: -3%). Pipe
// accounting says dur ~ SUM of HBM(31us) + LDS(25us) + VALU(8us): bursty
// phases, each pipe idle while another saturates. The untested variable
// (R4 was spill-confounded): NO LDS AT ALL.
//  - k[j][c] in the dots is a GROUP-UNIFORM address: as a global load the
//    coalescer collapses it to 4 unique 64B lines/wave-instr (1/group),
//    L1-resident across the 16-instr c-window (~4KB working set). The
//    dots' operand stream moves from the LDS pipe (shared with phase-2
//    shuffles) to the VMEM/L1 path that was idle during dots.
//  - Staging pass, ds_writes, and the last barrier deleted. Waves fully
//    independent -> phases naturally stagger across the CU.
//  - LDS=0: occupancy becomes VGPR-bound (~108 -> 4 waves/SIMD granted by
//    HW; __launch_bounds__(256,2) is only the allocator floor, proven to
//    land ~108 for this body in R13).
//  - Otherwise byte-identical to R13: qr prefetch, j-outer/c-inner dots,
//    cos-weight/normalize, shuffle phase 2, NT stores.
// Red line: WRITE_SIZE must stay 76,800 KB (spill detector).

namespace {

constexpr int W        = 15;             // block_size (rows per tile)
constexpr int CH       = 16;             // float4 per row (D=64)
constexpr int TILE4    = W * CH;         // 240 float4 per tile
constexpr int TPG      = 16;             // tiles per workgroup
constexpr int NTHREADS = 256;

typedef float f32x4_n __attribute__((ext_vector_type(4)));

__device__ __forceinline__ float4 relu4(float4 a) {
    return make_float4(fmaxf(a.x, 0.f), fmaxf(a.y, 0.f),
                       fmaxf(a.z, 0.f), fmaxf(a.w, 0.f));
}

__global__ __launch_bounds__(NTHREADS, 2)
void robust_attn_kernel(const float4* __restrict__ q4,
                        const float4* __restrict__ k4,
                        const float4* __restrict__ v4,
                        float4* __restrict__ o4,
                        int nblocks)
{
    const int tid  = threadIdx.x;
    const int lane = tid & 15;           // row l (ph1) / d-chunk (ph2)
    const int t    = tid >> 4;           // tile within WG
    const int g    = blockIdx.x * TPG + t;
    const bool active = (g < nblocks);
    const bool ph1    = active && (lane < W);

    // ---- (1) q rows into registers (scattered; proven ~3% vs staged) ------
    float4 qr[CH];
    {
        const float4* __restrict__ qp = q4 + (size_t)g * TILE4 + lane * CH;
#pragma unroll
        for (int c = 0; c < CH; ++c)
            qr[c] = ph1 ? qp[c] : make_float4(0.f, 0.f, 0.f, 0.f);
    }

    // ---- (2) phase 1: dots with k read DIRECT from global ----------------
    //      k[j][c] is group-uniform -> 4 unique 64B lines per wave-instr,
    //      L1-hit across the c-window. No LDS, no staging, no barrier.
    float s[W];
#pragma unroll
    for (int j = 0; j < W; ++j) s[j] = 0.f;

    if (ph1) {
#pragma unroll
        for (int c = 0; c < CH; ++c) qr[c] = relu4(qr[c]);

        const float4* __restrict__ kl = k4 + (size_t)g * TILE4;
#pragma unroll
        for (int j = 0; j < W; ++j) {
            float acc = 0.f;
#pragma unroll
            for (int c = 0; c < CH; ++c) {
                const float4 kk = relu4(kl[j * CH + c]);
                acc = fmaf(qr[c].x, kk.x, acc);
                acc = fmaf(qr[c].y, kk.y, acc);
                acc = fmaf(qr[c].z, kk.z, acc);
                acc = fmaf(qr[c].w, kk.w, acc);
            }
            s[j] = acc;
        }

        const int   l    = lane;
        const float step = 1.57079632679489662f / (float)W;  // (pi/2)/15
        float denom = 0.f;
#pragma unroll
        for (int j = 0; j < W; ++j) {
            float wc = __cosf(step * (float)(l - j));
            float tv = (j <= l) ? s[j] * wc : 0.f;
            s[j] = tv;
            denom += tv;
        }
        const float inv = 1.f / fmaxf(denom, 1e-6f);
#pragma unroll
        for (int j = 0; j < W; ++j) s[j] *= inv;
    }

    // ---- (3) phase 2: out = S @ relu(v); weights via wave shuffle ---------
    if (active) {
        const float4* __restrict__ vp = v4 + (size_t)g * TILE4 + lane;
        float4* __restrict__ op       = o4 + (size_t)g * TILE4 + lane;

        float4 vv[W];
#pragma unroll
        for (int j = 0; j < W; ++j) vv[j] = relu4(vp[j * CH]);

        const int tbase = tid & 48;   // tile base lane within the wave
#pragma unroll
        for (int l = 0; l < W; ++l) {
            float ax = 0.f, ay = 0.f, az = 0.f, aw = 0.f;
#pragma unroll
            for (int j = 0; j <= l; ++j) {     // causal
                const float w = __shfl(s[j], tbase + l, 64);
                ax = fmaf(w, vv[j].x, ax);
                ay = fmaf(w, vv[j].y, ay);
                az = fmaf(w, vv[j].z, az);
                aw = fmaf(w, vv[j].w, aw);
            }
            // nontemporal: output stream must not evict L3-resident inputs
            f32x4_n val = {ax, ay, az, aw};
            __builtin_nontemporal_store(val, (f32x4_n*)(op + l * CH));
        }
    }
}

}  // namespace

extern "C" void kernel_launch(void* const* d_in, const int* in_sizes, int n_in,
                              void* d_out, int out_size, void* d_ws, size_t ws_size,
                              hipStream_t stream) {
    const float4* q = (const float4*)d_in[0];
    const float4* k = (const float4*)d_in[1];
    const float4* v = (const float4*)d_in[2];
    float4* out = (float4*)d_out;

    const int total   = in_sizes[0];           // B*H*L*D
    const int nblocks = total / (W * CH * 4);  // 20480 for the bench shape
    const int wgs     = (nblocks + TPG - 1) / TPG;

    robust_attn_kernel<<<wgs, NTHREADS, 0, stream>>>(q, k, v, out, nblocks);
}

// Round 13
// 97.370 us; speedup vs baseline: 2.1897x; 2.1897x over previous
//
#include <hip/hip_runtime.h>

// RobustAttention: blockwise (w=15) causal cosFormer linear attention.
// scores[l,j] = cos(th_l - th_j) * <relu(q_l), relu(k_j)>, j<=l
// out[l] = sum_j scores[l,j] * relu(v_j) / max(sum_j scores[l,j], 1e-6)
//
// R16 = R15 (f16 MFMA rewrite) with two fixes:
//  - compile: __builtin_amdgcn_cvt_pkrtz returns __fp16x2, clashing with
//    _Float16 vectors. Replaced by scalar (_Float16) casts (compiler emits
//    v_cvt_f16_f32; m240: hand-packing isn't worth it). MFMA operands stay
//    _Float16x8 (accepted by the builtin in the failed compile).
//  - ordering: R15 had cross-lane V-transpose through wave-private LDS with
//    NO barrier, relying on compiler-preserved ds_write->ds_read program
//    order (the R9 lesson class). Now 2 unconditional __syncthreads()/tile
//    (RAW after staging, WAR after PV reads), work predicated inside, no
//    break (barrier-divergence safe; bench shape has no tail). R8/R10
//    proved __syncthreads doesn't poison regalloc; barrier cost ~0 here.
// Design (R15): per tile, S^T = K@Q^T via 2x mfma_f32_16x16x32_f16 (fp32
// accum); causal cos-weight + normalize in the verified C-layout
// (col=lane&15=l, row=4*g4+reg=j; denom = 2 shfl_xor); S A-frag rebuilt
// with 8 static-reg shuffles; PV = S@V via 4 mfma with V^T staged per-wave
// in LDS as packed f16 j-pairs (row stride 20 dwords; one aligned b128 per
// B-frag; k=16..31 region zeroed once). #pragma unroll 1 on the tile loop
// (R4/R14 hoist-spill killer).
// Risk (declared): f16 input quantization; absmax est 0.009-0.015.
// Red line: WRITE_SIZE must stay 76,800 KB.

namespace {

constexpr int W        = 15;             // block_size (rows per tile)
constexpr int CH       = 16;             // float4 per row (D=64)
constexpr int TILE4    = W * CH;         // 240 float4 per tile
constexpr int TPWAVE   = 4;              // tiles per wave
constexpr int NTHREADS = 256;            // 4 waves
constexpr int VTS      = 20;             // vt row stride (dwords): 16 data + 4 pad

using f16   = _Float16;
using f16x2 = _Float16 __attribute__((ext_vector_type(2)));
using f16x8 = _Float16 __attribute__((ext_vector_type(8)));
using f32x4 = float __attribute__((ext_vector_type(4)));
using u32x4 = unsigned int __attribute__((ext_vector_type(4)));

// pack two relu'd floats into one dword of f16 pair (for LDS staging)
__device__ __forceinline__ unsigned int pkrelu_u(float lo, float hi) {
    f16x2 h;
    h[0] = (f16)fmaxf(lo, 0.f);
    h[1] = (f16)fmaxf(hi, 0.f);
    return __builtin_bit_cast(unsigned int, h);
}

// Build an 8xf16 MFMA fragment from 8 consecutive relu'd fp32 (two float4).
__device__ __forceinline__ f16x8 frag8(const float4 a, const float4 b) {
    f16x8 r;
    r[0] = (f16)fmaxf(a.x, 0.f); r[1] = (f16)fmaxf(a.y, 0.f);
    r[2] = (f16)fmaxf(a.z, 0.f); r[3] = (f16)fmaxf(a.w, 0.f);
    r[4] = (f16)fmaxf(b.x, 0.f); r[5] = (f16)fmaxf(b.y, 0.f);
    r[6] = (f16)fmaxf(b.z, 0.f); r[7] = (f16)fmaxf(b.w, 0.f);
    return r;
}

__global__ __launch_bounds__(NTHREADS, 2)
void robust_attn_kernel(const float4* __restrict__ q4,
                        const float4* __restrict__ k4,
                        const float4* __restrict__ v4,
                        float* __restrict__ o,
                        int nblocks)
{
    __shared__ unsigned int vt[4][64 * VTS];   // 4 waves x 5,120 B = 20,480 B

    const int tid  = threadIdx.x;
    const int wid  = tid >> 6;                 // wave id
    const int lane = tid & 63;
    const int l16  = lane & 15;
    const int g4   = lane >> 4;                // quad 0..3

    unsigned int* __restrict__ vtw = vt[wid];  // wave-private slab

    // zero k=16..31 region of the PV B-operand once (never overwritten)
#pragma unroll
    for (int p = 8; p < 16; ++p) vtw[lane * VTS + p] = 0u;

    const float step = 1.57079632679489662f / 15.f;   // (pi/2)/15

#pragma unroll 1    // rolled: prevents cross-tile load hoisting (R4/R14 spills)
    for (int it = 0; it < TPWAVE; ++it) {
        const int g = ((int)blockIdx.x * 4 + wid) * TPWAVE + it;
        const bool work = (g < nblocks);

        f16x8 sf;                     // S A-fragment, built in part A
        bool  haveS = false;

        if (work) {
            const size_t tb = (size_t)g * TILE4;
            const float4 z4 = make_float4(0.f, 0.f, 0.f, 0.f);
            // row 15 of a tile aliases the next tile's row 0 (finite,
            // harmless: masked); zero it for the very last tile.
            const bool rowOK = (l16 < 15) || (g + 1 < nblocks);

            // ---- issue all global loads for this tile --------------------
            const float4* __restrict__ kp = k4 + tb + l16 * CH + g4 * 2;
            const float4* __restrict__ qp = q4 + tb + l16 * CH + g4 * 2;
            const float4 ka0 = rowOK ? kp[0] : z4, ka1 = rowOK ? kp[1] : z4;
            const float4 kb0 = rowOK ? kp[8] : z4, kb1 = rowOK ? kp[9] : z4;
            const float4 qa0 = rowOK ? qp[0] : z4, qa1 = rowOK ? qp[1] : z4;
            const float4 qb0 = rowOK ? qp[8] : z4, qb1 = rowOK ? qp[9] : z4;

            const int c  = l16;               // d-chunk (float4) for V staging
            const int j2 = g4;                // j-pair index 0..3 (+4 second)
            const float4 va0 = v4[tb + (2 * j2) * CH + c];
            const float4 vb0 = v4[tb + (2 * j2 + 1) * CH + c];
            const float4 va1 = v4[tb + (2 * (j2 + 4)) * CH + c];
            const float4 vb1 = (2 * (j2 + 4) + 1 < W)
                                   ? v4[tb + (2 * (j2 + 4) + 1) * CH + c] : z4;

            // ---- stage V^T as packed f16 j-pairs:
            //      vt[d][j2] = (v[2j2][d], v[2j2+1][d])
            {
                unsigned int* b0 = vtw + (4 * c) * VTS + j2;
                b0[0 * VTS] = pkrelu_u(va0.x, vb0.x);
                b0[1 * VTS] = pkrelu_u(va0.y, vb0.y);
                b0[2 * VTS] = pkrelu_u(va0.z, vb0.z);
                b0[3 * VTS] = pkrelu_u(va0.w, vb0.w);
                unsigned int* b1 = b0 + 4;
                b1[0 * VTS] = pkrelu_u(va1.x, vb1.x);
                b1[1 * VTS] = pkrelu_u(va1.y, vb1.y);
                b1[2 * VTS] = pkrelu_u(va1.z, vb1.z);
                b1[3 * VTS] = pkrelu_u(va1.w, vb1.w);
            }

            // ---- S^T = K @ Q^T (2 mfma, fp32 accumulate) -----------------
            f32x4 accs = {0.f, 0.f, 0.f, 0.f};
            accs = __builtin_amdgcn_mfma_f32_16x16x32_f16(
                       frag8(ka0, ka1), frag8(qa0, qa1), accs, 0, 0, 0);
            accs = __builtin_amdgcn_mfma_f32_16x16x32_f16(
                       frag8(kb0, kb1), frag8(qb0, qb1), accs, 0, 0, 0);

            // ---- causal cos-weight + normalize (l=l16, j=4*g4+reg) -------
            float sn0, sn1, sn2, sn3;
            {
                const int j0 = 4 * g4;
                float t0 = (j0 + 0 <= l16) ? accs[0] * __cosf(step * (float)(l16 - j0 - 0)) : 0.f;
                float t1 = (j0 + 1 <= l16) ? accs[1] * __cosf(step * (float)(l16 - j0 - 1)) : 0.f;
                float t2 = (j0 + 2 <= l16) ? accs[2] * __cosf(step * (float)(l16 - j0 - 2)) : 0.f;
                float t3 = (j0 + 3 <= l16) ? accs[3] * __cosf(step * (float)(l16 - j0 - 3)) : 0.f;
                float denom = (t0 + t1) + (t2 + t3);
                denom += __shfl_xor(denom, 16, 64);
                denom += __shfl_xor(denom, 32, 64);
                const float inv = 1.f / fmaxf(denom, 1e-6f);
                sn0 = t0 * inv; sn1 = t1 * inv; sn2 = t2 * inv; sn3 = t3 * inv;
            }

            // ---- build S A-frag: lane holds S[l=l16][j = 8*g4 + 0..7] ----
            {
                const int s0 = ((g4 << 1) << 4) | l16;   // src lanes m=0..3
                const int s1 = s0 + 16;                  // src lanes m=4..7
                float m0 = __shfl(sn0, s0, 64), m1 = __shfl(sn1, s0, 64);
                float m2 = __shfl(sn2, s0, 64), m3 = __shfl(sn3, s0, 64);
                float m4 = __shfl(sn0, s1, 64), m5 = __shfl(sn1, s1, 64);
                float m6 = __shfl(sn2, s1, 64), m7 = __shfl(sn3, s1, 64);
                if (g4 >= 2) { m0=m1=m2=m3=m4=m5=m6=m7 = 0.f; }   // j>=16
                sf[0] = (f16)m0; sf[1] = (f16)m1; sf[2] = (f16)m2; sf[3] = (f16)m3;
                sf[4] = (f16)m4; sf[5] = (f16)m5; sf[6] = (f16)m6; sf[7] = (f16)m7;
            }
            haveS = true;
        }

        __syncthreads();   // RAW: V^T staging visible before PV reads

        if (work && haveS) {
            // ---- PV: out = S @ V over 4 n-tiles of 16 columns ------------
#pragma unroll
            for (int nt = 0; nt < 4; ++nt) {
                const u32x4 bd =
                    *(const u32x4*)(vtw + (nt * 16 + l16) * VTS + g4 * 4);
                const f16x8 bf = __builtin_bit_cast(f16x8, bd);
                f32x4 acco = {0.f, 0.f, 0.f, 0.f};
                acco = __builtin_amdgcn_mfma_f32_16x16x32_f16(
                           sf, bf, acco, 0, 0, 0);

                // D: col=l16 (d within tile), row=4*g4+reg (=l); skip l=15
                float* __restrict__ ob =
                    o + (size_t)g * 960 + nt * 16 + l16;
                __builtin_nontemporal_store(acco[0], ob + (4 * g4 + 0) * 64);
                __builtin_nontemporal_store(acco[1], ob + (4 * g4 + 1) * 64);
                __builtin_nontemporal_store(acco[2], ob + (4 * g4 + 2) * 64);
                if (g4 < 3)
                    __builtin_nontemporal_store(acco[3], ob + (4 * g4 + 3) * 64);
            }
        }

        __syncthreads();   // WAR: PV reads done before next tile's staging
    }
}

}  // namespace

extern "C" void kernel_launch(void* const* d_in, const int* in_sizes, int n_in,
                              void* d_out, int out_size, void* d_ws, size_t ws_size,
                              hipStream_t stream) {
    const float4* q = (const float4*)d_in[0];
    const float4* k = (const float4*)d_in[1];
    const float4* v = (const float4*)d_in[2];
    float* out = (float*)d_out;

    const int total   = in_sizes[0];           // B*H*L*D
    const int nblocks = total / (W * CH * 4);  // 20480 for the bench shape
    const int tiles_per_wg = 4 * TPWAVE;       // 16
    const int wgs = (nblocks + tiles_per_wg - 1) / tiles_per_wg;

    robust_attn_kernel<<<wgs, NTHREADS, 0, stream>>>(q, k, v, out, nblocks);
}